// Round 7
// baseline (1231.398 us; speedup 1.0000x reference)
//
#include <hip/hip_runtime.h>

typedef unsigned int uint32;

__device__ __forceinline__ float fexp2(float x) { return __builtin_amdgcn_exp2f(x); }
__device__ __forceinline__ float flog2(float x) { return __builtin_amdgcn_logf(x); }

__device__ __forceinline__ float s2lin(float c) {
    float p = fexp2(flog2((c + 0.055f) * (1.0f / 1.055f)) * 2.4f);
    return c > 0.04045f ? p : c * (1.0f / 12.92f);
}

__device__ __forceinline__ float labf(float t) {
    float p = fexp2(flog2(t) * (1.0f / 3.0f));
    return t > 0.008856f ? p : 7.787f * t + (16.0f / 116.0f);
}

__device__ __forceinline__ void px(float r, float g, float b,
                                   float& L, float& a01, float& b01) {
    float lr = s2lin(r), lg = s2lin(g), lb = s2lin(b);
    // RGB2XYZ rows pre-divided by D65 white (0.95047, 1.0, 1.08883)
    float X = 0.43395300f * lr + 0.37621900f * lg + 0.18982460f * lb;
    float Y = 0.21267100f * lr + 0.71516000f * lg + 0.07216900f * lb;
    float Z = 0.01775660f * lr + 0.10946970f * lg + 0.87270740f * lb;
    float fx = labf(X), fy = labf(Y), fz = labf(Z);
    L   = 116.0f * fy - 16.0f;                              // L in [0,100]
    a01 = (500.0f * (fx - fy) + 128.0f) * (1.0f / 255.0f);
    b01 = (200.0f * (fy - fz) + 128.0f) * (1.0f / 255.0f);
}

__device__ __forceinline__ uint32 packpx(float L, float a01, float b01) {
    uint32 au = (uint32)(a01 * 255.0f + 0.5f);
    uint32 bu = (uint32)(b01 * 255.0f + 0.5f);
    unsigned short hb = __builtin_bit_cast(unsigned short, (_Float16)L);
    return au | (bu << 8) | ((uint32)hb << 16);
}

// ws layout (u32 units):
//   [0, 1024)            per-image arrival counters (512 used), zeroed by memsetAsync
//   [1024, 9216)         partial mins: (img*8+sub)*2 -> {min L, min(100-L)} f32
//   [16384, ...)         packed px: img*16384 + sub*2048 + p  (u8 a | u8 b<<8 | f16 L<<16)
#define WS_PX_OFF 16384

// 4096 blocks x 256 threads, 8 blocks/image (R0's proven shape: 48 VGPR, no
// spill -- packed px written immediately per-pixel, NO pk[] array; that array
// caused the R4/R5 spills). Last-arriving block per image (threadfence +
// atomicAdd protocol, verified correct in R5) rescales from L3-hot packed data
// and writes the image's output. Finishers of early images overlap main-phase
// of later images: small independent blocks, no convoy, no grid sync -- breaks
// the 1024-thread monolith's 68-78 us sum-of-phases plateau (R1/R3/R6).
__global__ __launch_bounds__(256) void k_one(const float* __restrict__ x,
                                             float* __restrict__ out,
                                             uint32* __restrict__ ws) {
    __shared__ float lds[6144];   // 24 KB = 2048 px
    __shared__ float sm[8];
    __shared__ uint32 last;
    const int bid = blockIdx.x, t = threadIdx.x;
    const int img = bid >> 3, sub = bid & 7;

    // stage this block's 2048-px slice: 6 x float4 per thread
    const float4* __restrict__ in4 =
        (const float4*)x + (size_t)img * 12288 + (size_t)sub * 1536;
    float4* l4 = (float4*)lds;
#pragma unroll
    for (int j = 0; j < 6; ++j) l4[t + 256 * j] = in4[t + 256 * j];
    __syncthreads();

    uint32* __restrict__ wpx = ws + WS_PX_OFF + (size_t)img * 16384 + (size_t)sub * 2048;
    float m1 = 3.4e38f, m2 = 3.4e38f;          // min(L), min(100-L)
#pragma unroll
    for (int i = 0; i < 8; ++i) {
        const int p = t + (i << 8);
        float L, a01, b01;
        px(lds[3 * p], lds[3 * p + 1], lds[3 * p + 2], L, a01, b01);  // 2-way bank: free
        m1 = fminf(m1, L);
        m2 = fminf(m2, 100.0f - L);
        wpx[p] = packpx(L, a01, b01);          // unit-stride u32 store, no reg array
    }

    // wave reduce (64 lanes), then 4-wave LDS reduce
#pragma unroll
    for (int m = 32; m; m >>= 1) {
        m1 = fminf(m1, __shfl_xor(m1, m, 64));
        m2 = fminf(m2, __shfl_xor(m2, m, 64));
    }
    if ((t & 63) == 0) { sm[(t >> 6) * 2] = m1; sm[(t >> 6) * 2 + 1] = m2; }
    __syncthreads();
    if (t == 0) {
        float* hdr = (float*)(ws + 1024) + ((size_t)img * 8 + sub) * 2;
        hdr[0] = fminf(fminf(sm[0], sm[2]), fminf(sm[4], sm[6]));
        hdr[1] = fminf(fminf(sm[1], sm[3]), fminf(sm[5], sm[7]));
        __threadfence();                        // release: packed px + mins visible
        last = atomicAdd(ws + img, 1u);         // device-scope
    }
    __syncthreads();
    if (last != 7u) return;                     // not last: exit, free the CU
    __threadfence();                            // acquire on every finisher thread

    // ---- finisher: whole-image rescale + store ----
    const float* hdr = (const float*)(ws + 1024) + (size_t)img * 16;
    float Lmin = 3.4e38f, M2 = 3.4e38f;
#pragma unroll
    for (int i = 0; i < 8; ++i) {
        Lmin = fminf(Lmin, hdr[2 * i]);
        M2   = fminf(M2,   hdr[2 * i + 1]);
    }
    const float s = 1.0f / ((100.0f - M2) - Lmin);

    const uint4* __restrict__ rp4 = (const uint4*)(ws + WS_PX_OFF + (size_t)img * 16384);
    float4* __restrict__ o4 = (float4*)out + (size_t)img * 12288;
#pragma unroll 4
    for (int g = 0; g < 16; ++g) {
        const int k = t + (g << 8);             // uint4 index -> px 4k..4k+3
        const uint4 v = rp4[k];                 // L3/L2-hot (written us ago)
        const uint32 w[4] = {v.x, v.y, v.z, v.w};
        float L[4], a[4], b[4];
#pragma unroll
        for (int i = 0; i < 4; ++i) {
            a[i] = (float)(w[i] & 255u) * (1.0f / 255.0f);
            b[i] = (float)((w[i] >> 8) & 255u) * (1.0f / 255.0f);
            L[i] = ((float)__builtin_bit_cast(_Float16, (unsigned short)(w[i] >> 16)) - Lmin) * s;
        }
        o4[3 * k]     = make_float4(L[0], a[0], b[0], L[1]);   // 48 B/lane contiguous
        o4[3 * k + 1] = make_float4(a[1], b[1], L[2], a[2]);
        o4[3 * k + 2] = make_float4(b[2], L[3], a[3], b[3]);
    }
}

// ---- fallback: round-1 fused kernel (verified) if ws too small ----
__global__ __launch_bounds__(1024) void k_fb(const float* __restrict__ x,
                                             float* __restrict__ out) {
    const int img = blockIdx.x, t = threadIdx.x;
    const size_t base = (size_t)img * 49152;
    const float* __restrict__ in = x + base;
    float* __restrict__ o = out + base;

    uint32 pk[16];
    float m1 = 3.4e38f, m2 = 3.4e38f;
#pragma unroll
    for (int i = 0; i < 16; ++i) {
        const int p = t + (i << 10);
        const float* q = in + 3 * p;
        float L, a01, b01;
        px(q[0], q[1], q[2], L, a01, b01);
        m1 = fminf(m1, L);
        m2 = fminf(m2, 100.0f - L);
        pk[i] = packpx(L, a01, b01);
    }
#pragma unroll
    for (int m = 32; m; m >>= 1) {
        m1 = fminf(m1, __shfl_xor(m1, m, 64));
        m2 = fminf(m2, __shfl_xor(m2, m, 64));
    }
    __shared__ float sm[32];
    if ((t & 63) == 0) { sm[(t >> 6) * 2] = m1; sm[(t >> 6) * 2 + 1] = m2; }
    __syncthreads();
    float Lmin = 3.4e38f, M2 = 3.4e38f;
#pragma unroll
    for (int i = 0; i < 16; ++i) {
        Lmin = fminf(Lmin, sm[2 * i]);
        M2   = fminf(M2,   sm[2 * i + 1]);
    }
    const float s = 1.0f / ((100.0f - M2) - Lmin);
#pragma unroll
    for (int i = 0; i < 16; ++i) {
        const int p = t + (i << 10);
        const uint32 v = pk[i];
        float* q = o + 3 * p;
        q[0] = ((float)__builtin_bit_cast(_Float16, (unsigned short)(v >> 16)) - Lmin) * s;
        q[1] = (float)(v & 255u) * (1.0f / 255.0f);
        q[2] = (float)((v >> 8) & 255u) * (1.0f / 255.0f);
    }
}

extern "C" void kernel_launch(void* const* d_in, const int* in_sizes, int n_in,
                              void* d_out, int out_size, void* d_ws, size_t ws_size,
                              hipStream_t stream) {
    (void)in_sizes; (void)n_in; (void)out_size;
    const float* x = (const float*)d_in[0];
    float* out = (float*)d_out;
    const size_t need = (size_t)WS_PX_OFF * 4 + 512ull * 16384ull * 4ull;
    if (ws_size >= need) {
        hipMemsetAsync(d_ws, 0, 4096, stream);   // zero arrival counters (capture-safe)
        k_one<<<4096, 256, 0, stream>>>(x, out, (uint32*)d_ws);
    } else {
        k_fb<<<512, 1024, 0, stream>>>(x, out);
    }
}

// Round 8
// 186.663 us; speedup vs baseline: 6.5969x; 6.5969x over previous
//
#include <hip/hip_runtime.h>

__device__ __forceinline__ float fexp2(float x) { return __builtin_amdgcn_exp2f(x); }
__device__ __forceinline__ float flog2(float x) { return __builtin_amdgcn_logf(x); }

__device__ __forceinline__ float s2lin(float c) {
    float p = fexp2(flog2((c + 0.055f) * (1.0f / 1.055f)) * 2.4f);
    return c > 0.04045f ? p : c * (1.0f / 12.92f);
}

__device__ __forceinline__ float labf(float t) {
    float p = fexp2(flog2(t) * (1.0f / 3.0f));
    return t > 0.008856f ? p : 7.787f * t + (16.0f / 116.0f);
}

__device__ __forceinline__ void px(float r, float g, float b,
                                   float& L, float& a01, float& b01) {
    float lr = s2lin(r), lg = s2lin(g), lb = s2lin(b);
    // RGB2XYZ rows pre-divided by D65 white (0.95047, 1.0, 1.08883)
    float X = 0.43395300f * lr + 0.37621900f * lg + 0.18982460f * lb;
    float Y = 0.21267100f * lr + 0.71516000f * lg + 0.07216900f * lb;
    float Z = 0.01775660f * lr + 0.10946970f * lg + 0.87270740f * lb;
    float fx = labf(X), fy = labf(Y), fz = labf(Z);
    L   = 116.0f * fy - 16.0f;                              // L in [0,100]
    a01 = (500.0f * (fx - fy) + 128.0f) * (1.0f / 255.0f);
    b01 = (200.0f * (fy - fz) + 128.0f) * (1.0f / 255.0f);
}

// L only: Y row + one labf (8 transcendentals/px vs 12). Bitwise identical to
// the L that px() computes (same instruction sequence on the same inputs).
__device__ __forceinline__ float Lonly(float r, float g, float b) {
    float lr = s2lin(r), lg = s2lin(g), lb = s2lin(b);
    float Y = 0.21267100f * lr + 0.71516000f * lg + 0.07216900f * lb;
    return 116.0f * labf(Y) - 16.0f;
}

// Two-pass, recompute instead of intermediate:
//   k1_min : read x cold (96 MB), L-only compute, per-block {minL, min(100-L)}
//            -> ws (32 KB). No pixel data stored.
//   k2_full: read 8 min-pairs (64 B) + x again (L3-hit: 96 MB fits in 256 MB
//            Infinity Cache, nothing evicts it between the two dispatches),
//            full Lab, rescale L inline, write out (96 MB).
// Kernel boundary = free device-scope release/acquire (R7's explicit
// threadfence protocol forced 4096 serialized L2 flushes -> 1267 us).
// Small-block shape (R0-proven: 256 thr, 24 KB LDS, ~48 VGPR, many blocks/CU
// co-resident) -- the 1024-thr monolith plateaued at 68-78 us sum-of-phases.

__global__ __launch_bounds__(256) void k1_min(const float* __restrict__ x,
                                              float* __restrict__ hdr) {
    __shared__ float lds[6144];   // 24 KB = 2048 px
    __shared__ float sm[8];
    const int b = blockIdx.x, t = threadIdx.x;
    const int img = b >> 3, sub = b & 7;
    const float4* __restrict__ in4 =
        (const float4*)x + (size_t)img * 12288 + (size_t)sub * 1536;
    float4* l4 = (float4*)lds;
#pragma unroll
    for (int j = 0; j < 6; ++j) l4[t + 256 * j] = in4[t + 256 * j];
    __syncthreads();

    float m1 = 3.4e38f, m2 = 3.4e38f;          // min(L), min(100-L)
#pragma unroll
    for (int i = 0; i < 8; ++i) {
        const int p = t + (i << 8);
        const float L = Lonly(lds[3 * p], lds[3 * p + 1], lds[3 * p + 2]);
        m1 = fminf(m1, L);
        m2 = fminf(m2, 100.0f - L);
    }
#pragma unroll
    for (int m = 32; m; m >>= 1) {
        m1 = fminf(m1, __shfl_xor(m1, m, 64));
        m2 = fminf(m2, __shfl_xor(m2, m, 64));
    }
    if ((t & 63) == 0) { sm[(t >> 6) * 2] = m1; sm[(t >> 6) * 2 + 1] = m2; }
    __syncthreads();
    if (t == 0) {
        hdr[((size_t)img * 8 + sub) * 2] =
            fminf(fminf(sm[0], sm[2]), fminf(sm[4], sm[6]));
        hdr[((size_t)img * 8 + sub) * 2 + 1] =
            fminf(fminf(sm[1], sm[3]), fminf(sm[5], sm[7]));
    }
}

__global__ __launch_bounds__(256) void k2_full(const float* __restrict__ x,
                                               float* __restrict__ out,
                                               const float* __restrict__ hdr0) {
    __shared__ float lds[6144];
    const int b = blockIdx.x, t = threadIdx.x;
    const int img = b >> 3, sub = b & 7;

    const float* hdr = hdr0 + (size_t)img * 16;
    float Lmin = 3.4e38f, m2 = 3.4e38f;
#pragma unroll
    for (int i = 0; i < 8; ++i) {              // 64 B, broadcast across the image's blocks
        Lmin = fminf(Lmin, hdr[2 * i]);
        m2   = fminf(m2,   hdr[2 * i + 1]);
    }
    const float s = 1.0f / ((100.0f - m2) - Lmin);

    const float4* __restrict__ in4 =
        (const float4*)x + (size_t)img * 12288 + (size_t)sub * 1536;
    float4* l4 = (float4*)lds;
#pragma unroll
    for (int j = 0; j < 6; ++j) l4[t + 256 * j] = in4[t + 256 * j];   // L3-hot
    __syncthreads();

#pragma unroll
    for (int i = 0; i < 8; ++i) {
        const int p = t + (i << 8);
        float L, a01, b01;
        px(lds[3 * p], lds[3 * p + 1], lds[3 * p + 2], L, a01, b01);
        lds[3 * p]     = (L - Lmin) * s;       // own slots: race-free (R0-proven)
        lds[3 * p + 1] = a01;
        lds[3 * p + 2] = b01;
    }
    __syncthreads();
    float4* __restrict__ o4 =
        (float4*)out + (size_t)img * 12288 + (size_t)sub * 1536;
#pragma unroll
    for (int j = 0; j < 6; ++j) o4[t + 256 * j] = l4[t + 256 * j];
}

// ---- fallback: round-1 monolith (verified, 68 us) if ws < 32 KB ----
typedef unsigned int uint32;
__global__ __launch_bounds__(1024) void k_fb(const float* __restrict__ x,
                                             float* __restrict__ out) {
    const int img = blockIdx.x, t = threadIdx.x;
    const size_t base = (size_t)img * 49152;
    const float* __restrict__ in = x + base;
    float* __restrict__ o = out + base;

    uint32 pk[16];
    float m1 = 3.4e38f, m2 = 3.4e38f;
#pragma unroll
    for (int i = 0; i < 16; ++i) {
        const int p = t + (i << 10);
        const float* q = in + 3 * p;
        float L, a01, b01;
        px(q[0], q[1], q[2], L, a01, b01);
        m1 = fminf(m1, L);
        m2 = fminf(m2, 100.0f - L);
        uint32 au = (uint32)(a01 * 255.0f + 0.5f);
        uint32 bu = (uint32)(b01 * 255.0f + 0.5f);
        unsigned short hb = __builtin_bit_cast(unsigned short, (_Float16)L);
        pk[i] = au | (bu << 8) | ((uint32)hb << 16);
    }
#pragma unroll
    for (int m = 32; m; m >>= 1) {
        m1 = fminf(m1, __shfl_xor(m1, m, 64));
        m2 = fminf(m2, __shfl_xor(m2, m, 64));
    }
    __shared__ float sm[32];
    if ((t & 63) == 0) { sm[(t >> 6) * 2] = m1; sm[(t >> 6) * 2 + 1] = m2; }
    __syncthreads();
    float Lmin = 3.4e38f, M2 = 3.4e38f;
#pragma unroll
    for (int i = 0; i < 16; ++i) {
        Lmin = fminf(Lmin, sm[2 * i]);
        M2   = fminf(M2,   sm[2 * i + 1]);
    }
    const float s = 1.0f / ((100.0f - M2) - Lmin);
#pragma unroll
    for (int i = 0; i < 16; ++i) {
        const int p = t + (i << 10);
        const uint32 v = pk[i];
        float* q = o + 3 * p;
        q[0] = ((float)__builtin_bit_cast(_Float16, (unsigned short)(v >> 16)) - Lmin) * s;
        q[1] = (float)(v & 255u) * (1.0f / 255.0f);
        q[2] = (float)((v >> 8) & 255u) * (1.0f / 255.0f);
    }
}

extern "C" void kernel_launch(void* const* d_in, const int* in_sizes, int n_in,
                              void* d_out, int out_size, void* d_ws, size_t ws_size,
                              hipStream_t stream) {
    (void)in_sizes; (void)n_in; (void)out_size;
    const float* x = (const float*)d_in[0];
    float* out = (float*)d_out;
    if (ws_size >= 512ull * 8ull * 2ull * sizeof(float)) {
        float* hdr = (float*)d_ws;
        k1_min<<<4096, 256, 0, stream>>>(x, hdr);
        k2_full<<<4096, 256, 0, stream>>>(x, out, hdr);
    } else {
        k_fb<<<512, 1024, 0, stream>>>(x, out);
    }
}